// Round 1
// baseline (153.762 us; speedup 1.0000x reference)
//
#include <hip/hip_runtime.h>
#include <stdint.h>
#include <math.h>

// RouterLinear: C[b,o] = bias[o] + sum_k W[o, idx[b,k]] * x[b,k]; top-64 per
// row (values desc, tie -> lower index); outputs vals (f32) then indices (as
// float). fp64 accumulation, k-ascending -> matches np float64 (absmax 0).
//
// R8: widen gemm blocks 4 -> 8 output rows, two 64KB swizzled LDS tiles
// (128KB dynamic LDS, 1 block/CU, 16 waves). Same LDS bytes/conflicts, but
// 2x ILP per wave (two gathers + 8 FMAs per offset extraction), halved grid
// -> halved offs8/xs4 L2 stream traffic, full 64B C-lines per lane. Attacks
// the scheduling slack (R7: 51us with LDS ~55%, VALU 35%, nothing saturated).

#define NB    1024
#define NIN   4096
#define NOUT  4096
#define NK    64
#define NTOPK 64

__device__ __forceinline__ int SWZ(int i) { return i ^ ((i >> 3) & 7); }

// ---------------------------------------------------------------- pack ------
// offs8[k8*1024 + b] : uint4 = 8 packed ushorts  (SWZ(idx[b][8k8+j])<<4)
// xs4 [k4*1024 + b]  : float4 = x[b][4k4 .. 4k4+3]
__global__ __launch_bounds__(256) void pack_kernel(const float* __restrict__ x,
                                                   const int* __restrict__ idx,
                                                   uint4* __restrict__ offs8,
                                                   float4* __restrict__ xs4) {
    int tid = blockIdx.x * 256 + threadIdx.x;   // 8192 threads: (b, k8)
    int b  = tid >> 3;
    int k8 = tid & 7;
    const int4* ip = reinterpret_cast<const int4*>(idx + (b << 6) + (k8 << 3));
    const float4* xp = reinterpret_cast<const float4*>(x + (b << 6) + (k8 << 3));
    int4 ia = ip[0], ib = ip[1];
    float4 xa = xp[0], xb = xp[1];

    unsigned o0 = (unsigned)(SWZ(ia.x) << 4), o1 = (unsigned)(SWZ(ia.y) << 4);
    unsigned o2 = (unsigned)(SWZ(ia.z) << 4), o3 = (unsigned)(SWZ(ia.w) << 4);
    unsigned o4 = (unsigned)(SWZ(ib.x) << 4), o5 = (unsigned)(SWZ(ib.y) << 4);
    unsigned o6 = (unsigned)(SWZ(ib.z) << 4), o7 = (unsigned)(SWZ(ib.w) << 4);

    offs8[(k8 << 10) + b] = make_uint4(o0 | (o1 << 16), o2 | (o3 << 16),
                                       o4 | (o5 << 16), o6 | (o7 << 16));
    xs4[((k8 << 1) + 0) * 1024 + b] = xa;
    xs4[((k8 << 1) + 1) * 1024 + b] = xb;
}

// ---------------------------------------------------------------- gemm ------
// Block bo owns W rows [bo*8, bo*8+8) as TWO swizzled-transposed 64KB tiles
// (tile0 = rows 0..3, tile1 = rows 4..7) in 128KB dynamic LDS. 1024 threads,
// 1 b each, 1 block/CU (16 waves). Each packed offset feeds two independent
// b128 gathers (tile0 / tile0+64KB) and 8 fp64 FMAs sharing one x-convert.
__global__ __launch_bounds__(1024, 4) void gemm_kernel(const uint4* __restrict__ offs8,
                                                       const float4* __restrict__ xs4,
                                                       const float* __restrict__ W,
                                                       const float* __restrict__ bias,
                                                       double* __restrict__ C) {
    extern __shared__ float4 Wt[];   // 2 x 4096 float4 = 128 KB
    const int t  = threadIdx.x;
    const int o0 = blockIdx.x * 8;

    // Conflict-free staging: coalesced row loads (8 rows, col t), 4x4 register
    // transposes, swizzled b128 writes. Same proven pattern as R7, twice.
    {
        const float4* wp = reinterpret_cast<const float4*>(W) + (size_t)o0 * 1024 + t;
        float4 r0 = wp[0 * 1024], r1 = wp[1 * 1024], r2 = wp[2 * 1024], r3 = wp[3 * 1024];
        float4 r4 = wp[4 * 1024], r5 = wp[5 * 1024], r6 = wp[6 * 1024], r7 = wp[7 * 1024];
        int i0 = t << 2;
        Wt[SWZ(i0 + 0)] = make_float4(r0.x, r1.x, r2.x, r3.x);
        Wt[SWZ(i0 + 1)] = make_float4(r0.y, r1.y, r2.y, r3.y);
        Wt[SWZ(i0 + 2)] = make_float4(r0.z, r1.z, r2.z, r3.z);
        Wt[SWZ(i0 + 3)] = make_float4(r0.w, r1.w, r2.w, r3.w);
        Wt[4096 + SWZ(i0 + 0)] = make_float4(r4.x, r5.x, r6.x, r7.x);
        Wt[4096 + SWZ(i0 + 1)] = make_float4(r4.y, r5.y, r6.y, r7.y);
        Wt[4096 + SWZ(i0 + 2)] = make_float4(r4.z, r5.z, r6.z, r7.z);
        Wt[4096 + SWZ(i0 + 3)] = make_float4(r4.w, r5.w, r6.w, r7.w);
    }
    __syncthreads();

    double acc0[4], acc1[4];
#pragma unroll
    for (int r = 0; r < 4; ++r) {
        acc0[r] = (double)bias[o0 + r];
        acc1[r] = (double)bias[o0 + 4 + r];
    }

    const uint4*  op = offs8 + t;   // element k8*1024 + t
    const float4* xp = xs4 + t;     // element k4*1024 + t
    const char*   base0 = reinterpret_cast<const char*>(Wt);
    const char*   base1 = base0 + 65536;

    // One shared x->f64 convert feeds both tiles' gathers (8 FMAs).
#define CONSUME2(WA, WB, XV)                                                  \
    {                                                                         \
        double xd = (double)(XV);                                             \
        acc0[0] += xd * (double)(WA).x; acc0[1] += xd * (double)(WA).y;       \
        acc0[2] += xd * (double)(WA).z; acc0[3] += xd * (double)(WA).w;       \
        acc1[0] += xd * (double)(WB).x; acc1[1] += xd * (double)(WB).y;       \
        acc1[2] += xd * (double)(WB).z; acc1[3] += xd * (double)(WB).w;       \
    }

    // Software pipeline: next-iteration stream loads issue before this
    // iteration's gathers are consumed; gathers batched 4-wide (2 k-pairs).
    uint4  o8 = op[0];
    float4 xA = xp[0];
    float4 xB = xp[1024];

#pragma unroll 2
    for (int k8 = 0; k8 < NK / 8; ++k8) {
        int kn = (k8 + 1) & 7;               // last iter reloads k8=0 (harmless)
        uint4  o8n = op[kn << 10];
        float4 xAn = xp[kn << 11];
        float4 xBn = xp[(kn << 11) + 1024];

        {
            unsigned a0 = o8.x & 0xFFFFu, a1 = o8.x >> 16;
            float4 w0a = *reinterpret_cast<const float4*>(base0 + a0);
            float4 w0b = *reinterpret_cast<const float4*>(base1 + a0);
            float4 w1a = *reinterpret_cast<const float4*>(base0 + a1);
            float4 w1b = *reinterpret_cast<const float4*>(base1 + a1);
            CONSUME2(w0a, w0b, xA.x)
            CONSUME2(w1a, w1b, xA.y)
        }
        {
            unsigned a0 = o8.y & 0xFFFFu, a1 = o8.y >> 16;
            float4 w0a = *reinterpret_cast<const float4*>(base0 + a0);
            float4 w0b = *reinterpret_cast<const float4*>(base1 + a0);
            float4 w1a = *reinterpret_cast<const float4*>(base0 + a1);
            float4 w1b = *reinterpret_cast<const float4*>(base1 + a1);
            CONSUME2(w0a, w0b, xA.z)
            CONSUME2(w1a, w1b, xA.w)
        }
        {
            unsigned a0 = o8.z & 0xFFFFu, a1 = o8.z >> 16;
            float4 w0a = *reinterpret_cast<const float4*>(base0 + a0);
            float4 w0b = *reinterpret_cast<const float4*>(base1 + a0);
            float4 w1a = *reinterpret_cast<const float4*>(base0 + a1);
            float4 w1b = *reinterpret_cast<const float4*>(base1 + a1);
            CONSUME2(w0a, w0b, xB.x)
            CONSUME2(w1a, w1b, xB.y)
        }
        {
            unsigned a0 = o8.w & 0xFFFFu, a1 = o8.w >> 16;
            float4 w0a = *reinterpret_cast<const float4*>(base0 + a0);
            float4 w0b = *reinterpret_cast<const float4*>(base1 + a0);
            float4 w1a = *reinterpret_cast<const float4*>(base0 + a1);
            float4 w1b = *reinterpret_cast<const float4*>(base1 + a1);
            CONSUME2(w0a, w0b, xB.z)
            CONSUME2(w1a, w1b, xB.w)
        }

        o8 = o8n; xA = xAn; xB = xBn;
    }
#undef CONSUME2

    // 8 doubles = one full 64B line per lane.
    double2* dst = reinterpret_cast<double2*>(C + (size_t)t * NOUT + o0);
    dst[0] = make_double2(acc0[0], acc0[1]);
    dst[1] = make_double2(acc0[2], acc0[3]);
    dst[2] = make_double2(acc1[0], acc1[1]);
    dst[3] = make_double2(acc1[2], acc1[3]);
}

// ---------------------------------------------------------------- top-k -----
// Monotone fp32 key: double->float rounding preserves order, so the crossing
// bin over fp32 keys yields a superset of the true top-64; the exact fp64
// bitonic sort of candidates then matches np exactly.
__device__ __forceinline__ unsigned keyf(double d) {
    unsigned u = __float_as_uint((float)d);
    return (u & 0x80000000u) ? ~u : (u | 0x80000000u);
}
// Transposed hist layout: chunk scans (bin = t*16+q) become lane-consecutive.
__device__ __forceinline__ int HADDR(int bin) { return ((bin & 15) << 8) | (bin >> 4); }

__global__ __launch_bounds__(256) void topk_kernel(const double* __restrict__ C,
                                                   float* __restrict__ outv,
                                                   float* __restrict__ outi) {
    __shared__ unsigned hist[4096];    // 16 KB; bin = key>>20 (sign+exp8+mant3)
    __shared__ double   cval[1024];    // 8 KB
    __shared__ int      cidx[1024];    // 4 KB
    __shared__ unsigned part[256];     // 1 KB, chunk sums -> chunk suffixes
    __shared__ int      sBstar;
    __shared__ unsigned sCnt;

    const int t = threadIdx.x;
    const double2* row2 = reinterpret_cast<const double2*>(C + (size_t)blockIdx.x * NOUT);

    double v[16];
#pragma unroll
    for (int q = 0; q < 8; ++q) {
        double2 d = row2[q * 256 + t];
        v[2 * q] = d.x; v[2 * q + 1] = d.y;
    }

    for (int j = t; j < 4096; j += 256) hist[j] = 0u;
    if (t == 0) sCnt = 0u;
    __syncthreads();

#pragma unroll
    for (int q = 0; q < 16; ++q)
        atomicAdd(&hist[HADDR(keyf(v[q]) >> 20)], 1u);
    __syncthreads();

    {
        unsigned s = 0;
#pragma unroll
        for (int q = 0; q < 16; ++q) s += hist[(q << 8) | t];
        part[t] = s;
    }
    __syncthreads();

    if (t < 64) {
        unsigned c0 = part[4 * t + 0], c1 = part[4 * t + 1];
        unsigned c2 = part[4 * t + 2], c3 = part[4 * t + 3];
        unsigned s = c0 + c1 + c2 + c3;
        unsigned suf = s;
        for (int off = 1; off < 64; off <<= 1) {
            unsigned xx = __shfl_down(suf, off);
            if (t + off < 64) suf += xx;
        }
        unsigned below = suf - s;           // sum of chunks > 4t+3
        part[4 * t + 3] = below + c3;
        part[4 * t + 2] = below + c3 + c2;
        part[4 * t + 1] = below + c3 + c2 + c1;
        part[4 * t + 0] = below + s;
    }
    __syncthreads();

    {
        unsigned run = (t < 255) ? part[t + 1] : 0u;
#pragma unroll
        for (int q = 15; q >= 0; --q) {
            unsigned cge = run + hist[(q << 8) | t];
            if (cge >= 64u && run < 64u) sBstar = t * 16 + q;
            run = cge;
        }
    }
    __syncthreads();

    const unsigned Bstar = (unsigned)sBstar;
#pragma unroll
    for (int q = 0; q < 16; ++q) {
        if ((keyf(v[q]) >> 20) >= Bstar) {
            unsigned pos = atomicAdd(&sCnt, 1u);
            if (pos < 1024u) {
                cval[pos] = v[q];
                cidx[pos] = (q >> 1) * 512 + 2 * t + (q & 1);
            }
        }
    }
    __syncthreads();

    int M = (int)sCnt; if (M > 1024) M = 1024;
    int n = 64; while (n < M) n <<= 1;
    for (int j = M + t; j < n; j += 256) { cval[j] = -INFINITY; cidx[j] = 0x7fffffff; }
    __syncthreads();

    for (int kk = 2; kk <= n; kk <<= 1) {
        for (int jj = kk >> 1; jj > 0; jj >>= 1) {
            for (int i = t; i < n; i += 256) {
                int l = i ^ jj;
                if (l > i) {
                    double v1 = cval[i], v2 = cval[l];
                    int    i1 = cidx[i], i2 = cidx[l];
                    bool first = (v1 > v2) || (v1 == v2 && i1 < i2);
                    bool asc   = ((i & kk) == 0);
                    if (first != asc) {
                        cval[i] = v2; cval[l] = v1;
                        cidx[i] = i2; cidx[l] = i1;
                    }
                }
            }
            __syncthreads();
        }
    }

    if (t < 64) {
        outv[(blockIdx.x << 6) + t] = (float)cval[t];
        outi[(blockIdx.x << 6) + t] = (float)cidx[t];
    }
}

// ---------------------------------------------------------------- launch ----
extern "C" void kernel_launch(void* const* d_in, const int* in_sizes, int n_in,
                              void* d_out, int out_size, void* d_ws, size_t ws_size,
                              hipStream_t stream) {
    const float* x    = (const float*)d_in[0];
    const float* W    = (const float*)d_in[1];
    const float* bias = (const float*)d_in[2];
    const int*   idx  = (const int*)d_in[3];

    char*   ws    = (char*)d_ws;
    double* C     = (double*)ws;                                   // 32 MB
    uint4*  offs8 = (uint4*)(ws + (size_t)NB * NOUT * sizeof(double));          // 128 KB
    float4* xs4   = (float4*)(ws + (size_t)NB * NOUT * sizeof(double) + 131072); // 256 KB

    float* outv = (float*)d_out;
    float* outi = outv + NB * NTOPK;

    // One-time opt-in for 128KB dynamic LDS (host-side, graph-capture-safe).
    static int lds_ok = 0;
    if (!lds_ok) {
        hipFuncSetAttribute(reinterpret_cast<const void*>(gemm_kernel),
                            hipFuncAttributeMaxDynamicSharedMemorySize, 131072);
        lds_ok = 1;
    }

    pack_kernel<<<(NB * 8) / 256, 256, 0, stream>>>(x, idx, offs8, xs4);
    gemm_kernel<<<NOUT / 8, 1024, 131072, stream>>>(offs8, xs4, W, bias, C);
    topk_kernel<<<NB, 256, 0, stream>>>(C, outv, outi);
}